// Round 5
// baseline (453.543 us; speedup 1.0000x reference)
//
#include <hip/hip_runtime.h>
#include <stdint.h>

#define NROWS 8192   // B*S_LEN = 4*2048
#define INF   4096
#define OUTF  4096
#define RNK   1024

typedef unsigned short u16;
typedef __attribute__((ext_vector_type(8))) short bf16x8;   // 8 bf16 = 4 VGPRs
typedef __attribute__((ext_vector_type(4))) float f32x4;
typedef __attribute__((ext_vector_type(8))) unsigned short u16x8;

__device__ __forceinline__ u16 f32_bf16(float f) {
  union { float f; uint32_t u; } v; v.f = f;
  return (u16)((v.u + 0x7FFF + ((v.u >> 16) & 1)) >> 16);
}

// ---------------- conversion / dequant kernels (memory-bound) ----------------

__global__ __launch_bounds__(256) void convert_x(const float* __restrict__ x,
                                                 u16* __restrict__ o) {
  int t = blockIdx.x * 256 + threadIdx.x;
  int e = t * 8;
  float4 a = *(const float4*)(x + e);
  float4 b = *(const float4*)(x + e + 4);
  u16x8 r;
  r[0] = f32_bf16(a.x); r[1] = f32_bf16(a.y); r[2] = f32_bf16(a.z); r[3] = f32_bf16(a.w);
  r[4] = f32_bf16(b.x); r[5] = f32_bf16(b.y); r[6] = f32_bf16(b.z); r[7] = f32_bf16(b.w);
  *(u16x8*)(o + e) = r;
}

// Vh [RANK][INF]; fold dequantized S into rows of Vh.
__global__ __launch_bounds__(256) void dequant_vh(const int* __restrict__ vh,
                                                  const float* __restrict__ vs,
                                                  const float* __restrict__ vz,
                                                  const int* __restrict__ sd,
                                                  const float* __restrict__ ss,
                                                  const float* __restrict__ sz,
                                                  u16* __restrict__ o) {
  int t = blockIdx.x * 256 + threadIdx.x;
  int e = t * 4;
  int row = e >> 12;              // / INF
  float sval = ((float)sd[row] - sz[0]) * ss[0];
  float sc = vs[0] * sval;
  float zp = vz[0];
  int4 d = *(const int4*)(vh + e);
  ushort4 r;
  r.x = f32_bf16(((float)d.x - zp) * sc);
  r.y = f32_bf16(((float)d.y - zp) * sc);
  r.z = f32_bf16(((float)d.z - zp) * sc);
  r.w = f32_bf16(((float)d.w - zp) * sc);
  *(ushort4*)(o + e) = r;
}

// U [OUTF][RNK]
__global__ __launch_bounds__(256) void dequant_u(const int* __restrict__ ud,
                                                 const float* __restrict__ us,
                                                 const float* __restrict__ uz,
                                                 u16* __restrict__ o) {
  int t = blockIdx.x * 256 + threadIdx.x;
  int e = t * 4;
  float sc = us[0];
  float zp = uz[0];
  int4 d = *(const int4*)(ud + e);
  ushort4 r;
  r.x = f32_bf16(((float)d.x - zp) * sc);
  r.y = f32_bf16(((float)d.y - zp) * sc);
  r.z = f32_bf16(((float)d.z - zp) * sc);
  r.w = f32_bf16(((float)d.w - zp) * sc);
  *(ushort4*)(o + e) = r;
}

// ------------- m201-faithful 4-phase bf16 GEMM (T2+T3+T4+T5) -----------------
// C[m][n] = sum_k A[m][k]*B[n][k].  BM=256, BK=64, 512 threads = 8 waves.
//
// Round-5: faithful port of the verified 256^2 8-phase template (m201):
//  * per phase: {ds_reads for this quadrant | stage ONE half-tile} -> barrier
//    -> lgkmcnt(0) -> setprio(1) -> MFMA cluster -> setprio(0) -> barrier.
//    NO sched_barrier(0) pinning anywhere (m141: pinning cost -42%).
//  * stage ring at m201 depth: P1 stages B0(nbuf) for t+1; P2/P3/P4 stage
//    A0/B1/A1(buf) for t+2 -- each into the region freed by the PREVIOUS
//    phase's reads (>=1 barrier separation).  ONE vmcnt(4+LB) per tile (P4):
//    FIFO in flight there = {t-1:A0,B1,A1; t:B0,A0',B1',A1'} = 7 halves;
//    retiring to 3 halves (6 loads GEMM2 / 5 GEMM1) retires exactly the four
//    halves tile t+1 reads.  Never vmcnt(0) in the loop (T4).
//  * quadrant ring (0,0)->(0,1)->(1,1)->(1,0) with register reuse: reads per
//    phase = {A+B, B, A, 0} = m201's "4 or 8 (or 12) ds_read_b128" pattern.
// T1 XCD-chunked blockIdx swizzle kept (round-3: FETCH 266->74 MB).
// LDS XOR swizzle kept (chunk c of row r at c^(r&7), source pre-permuted,
// linear gl_lds dest); bank conflicts measured 0.

__device__ __forceinline__ void gl_lds16(const u16* g, u16* l) {
  __builtin_amdgcn_global_load_lds(
      (const __attribute__((address_space(1))) void*)g,
      (__attribute__((address_space(3))) void*)l, 16, 0, 0);
}

template <int VM> __device__ __forceinline__ void vm_wait() {
  static_assert(VM == 5 || VM == 6, "unexpected vmcnt");
  if constexpr (VM == 5) asm volatile("s_waitcnt vmcnt(5)" ::: "memory");
  if constexpr (VM == 6) asm volatile("s_waitcnt vmcnt(6)" ::: "memory");
}

template <int BN, int WM, int WN, int K, int N, bool OUT_BF16, bool ADD_BIAS>
__global__ __launch_bounds__(512, 2) void gemm5(const u16* __restrict__ A,
                                                const u16* __restrict__ B,
                                                void* __restrict__ Cv,
                                                const float* __restrict__ bias) {
  constexpr int BM = 256, BK = 64;
  constexpr int AR = 128 / WM;          // per-wave rows inside an A-half
  constexpr int BC = (BN / 2) / WN;     // per-wave cols inside a B-half
  constexpr int AI = AR / 16;           // A frags per quadrant
  constexpr int BJ = BC / 16;           // B frags per quadrant
  constexpr int LB = (BN == 256) ? 2 : 1;  // gl_lds per B half
  constexpr int NT = K / BK;
  constexpr int AH = 128 * BK;          // elems per A half (16 KiB)
  constexpr int BH = (BN / 2) * BK;     // elems per B half (16 or 8 KiB)
  constexpr int VMN = 4 + LB;           // loads kept in flight at tile end

  constexpr int NXB = N / BN;           // grid x (N-blocks)
  constexpr int NYB = NROWS / BM;       // grid y (M-blocks)
  constexpr int NWG = NXB * NYB;
  static_assert(NWG % 8 == 0, "XCD swizzle requires nwg % 8 == 0");
  constexpr int CPX = NWG / 8;          // blocks per XCD chunk

  __shared__ __attribute__((aligned(16))) u16 ldsA[2 * 2 * AH];
  __shared__ __attribute__((aligned(16))) u16 ldsB[2 * 2 * BH];

  const int tid  = threadIdx.x;
  const int lane = tid & 63;
  const int wave = tid >> 6;            // 0..7
  const int wn   = wave % WN;
  const int wm   = wave / WN;

  // T1: XCD-chunked swizzle (HW round-robins linear id % 8 across XCDs).
  const int L    = blockIdx.y * NXB + blockIdx.x;
  const int orig = (L & 7) * CPX + (L >> 3);
  const int bm   = (orig / NXB) * BM;
  const int bn   = (orig % NXB) * BN;

  // staging map: thread tid writes LDS bytes [tid*16] of a unit (linear, as
  // global_load_lds requires); fetches the swizzled global 16B chunk.
  const int srow = tid >> 3;            // 0..63
  const int spc  = tid & 7;             // physical 16B chunk
  const int sgc  = spc ^ (srow & 7);    // swizzled global chunk

  const u16* gA = A + (size_t)(bm + srow) * K + sgc * 8;
  const u16* gB = B + (size_t)(bn + srow) * K + sgc * 8;
  u16* lA = ldsA + srow * BK + spc * 8;
  u16* lB = ldsB + srow * BK + spc * 8;

#define STAGE_A(buf, h, kt)                                                    \
  { const u16* g_ = gA + (size_t)(h) * 128 * K + (kt);                         \
    u16* l_ = lA + ((buf) * 2 + (h)) * AH;                                     \
    gl_lds16(g_, l_);                                                          \
    gl_lds16(g_ + (size_t)64 * K, l_ + 64 * BK); }

#define STAGE_B(buf, h, kt)                                                    \
  { const u16* g_ = gB + (size_t)(h) * (BN / 2) * K + (kt);                    \
    u16* l_ = lB + ((buf) * 2 + (h)) * BH;                                     \
    gl_lds16(g_, l_);                                                          \
    if constexpr (LB == 2) gl_lds16(g_ + (size_t)64 * K, l_ + 64 * BK); }

  const int r   = lane & 15;
  const int kq  = (lane >> 4) * 8;
  const int pc0 = (((kq) >> 3) ^ (r & 7)) << 3;        // phys col, k-step 0
  const int pc1 = (((32 + kq) >> 3) ^ (r & 7)) << 3;   // phys col, k-step 1

  f32x4 acc[2][2][AI][BJ] = {};
  bf16x8 af[AI][2];    // A-half frags: hold A0 for q00/q01, reused for A1
  bf16x8 bf0[BJ][2];   // B-half0 frags, live whole K-tile (q00 and q10)
  bf16x8 bf1[BJ][2];   // B-half1 frags (q01, q11)

#define LOAD_A(buf, ih)                                                        \
  { const u16* ab = ldsA + ((buf) * 2 + (ih)) * AH + (wm * AR + r) * BK;       \
    _Pragma("unroll")                                                          \
    for (int i = 0; i < AI; ++i) {                                             \
      af[i][0] = *(const bf16x8*)(ab + i * 16 * BK + pc0);                     \
      af[i][1] = *(const bf16x8*)(ab + i * 16 * BK + pc1);                     \
    } }

#define LOAD_B(dst, buf, jh)                                                   \
  { const u16* bb = ldsB + ((buf) * 2 + (jh)) * BH + (wn * BC + r) * BK;       \
    _Pragma("unroll")                                                          \
    for (int j = 0; j < BJ; ++j) {                                             \
      dst[j][0] = *(const bf16x8*)(bb + j * 16 * BK + pc0);                    \
      dst[j][1] = *(const bf16x8*)(bb + j * 16 * BK + pc1);                    \
    } }

#define MFMA_Q(ih, jh, bsrc)                                                   \
  _Pragma("unroll")                                                            \
  for (int i = 0; i < AI; ++i)                                                 \
    _Pragma("unroll")                                                          \
    for (int j = 0; j < BJ; ++j) {                                             \
      acc[ih][jh][i][j] = __builtin_amdgcn_mfma_f32_16x16x32_bf16(             \
          af[i][0], bsrc[j][0], acc[ih][jh][i][j], 0, 0, 0);                   \
      acc[ih][jh][i][j] = __builtin_amdgcn_mfma_f32_16x16x32_bf16(             \
          af[i][1], bsrc[j][1], acc[ih][jh][i][j], 0, 0, 0);                   \
    }

#define BAR   __builtin_amdgcn_s_barrier()
#define LGKM0 asm volatile("s_waitcnt lgkmcnt(0)" ::: "memory")
#define PRIO1 __builtin_amdgcn_s_setprio(1)
#define PRIO0 __builtin_amdgcn_s_setprio(0)

  // prologue (m201): tile0's 4 halves, then tile1's {A0,B1,A1}; wait to VMN
  // (retires exactly tile0, keeps tile1's 3 staged halves in flight).
  STAGE_A(0, 0, 0);
  STAGE_B(0, 0, 0);
  STAGE_B(0, 1, 0);
  STAGE_A(0, 1, 0);
  constexpr int KT1 = (NT > 1 ? BK : 0);
  STAGE_A(1, 0, KT1);
  STAGE_B(1, 1, KT1);
  STAGE_A(1, 1, KT1);
  vm_wait<VMN>();
  BAR;

  for (int t = 0; t < NT; ++t) {
    const int buf  = t & 1;
    const int nbuf = buf ^ 1;
    const int kt1 = (t + 1 < NT ? t + 1 : NT - 1) * BK;  // clamp keeps vmcnt
    const int kt2 = (t + 2 < NT ? t + 2 : NT - 1) * BK;  // counts uniform

    // P1 (0,0): fresh A0 + B0; stage B0(nbuf) for t+1 (region idle since t-1)
    LOAD_A(buf, 0);
    LOAD_B(bf0, buf, 0);
    STAGE_B(nbuf, 0, kt1);
    if constexpr (AI * 2 + BJ * 2 >= 12)
      asm volatile("s_waitcnt lgkmcnt(8)" ::: "memory");
    BAR; LGKM0;
    PRIO1; MFMA_Q(0, 0, bf0); PRIO0;
    BAR;

    // P2 (0,1): fresh B1 (af reused); stage A0(buf) for t+2 (freed at P1)
    LOAD_B(bf1, buf, 1);
    STAGE_A(buf, 0, kt2);
    BAR; LGKM0;
    PRIO1; MFMA_Q(0, 1, bf1); PRIO0;
    BAR;

    // P3 (1,1): fresh A1 (bf1 reused); stage B1(buf) for t+2 (freed at P2)
    LOAD_A(buf, 1);
    STAGE_B(buf, 1, kt2);
    BAR; LGKM0;
    PRIO1; MFMA_Q(1, 1, bf1); PRIO0;
    BAR;

    // P4 (1,0): no reads (af=A1, bf0 reused); stage A1(buf) for t+2 (freed
    // at P3); tile-end counted wait retires exactly tile t+1's four halves.
    STAGE_A(buf, 1, kt2);
    BAR;
    PRIO1; MFMA_Q(1, 0, bf0); PRIO0;
    vm_wait<VMN>();
    BAR;
  }

  // epilogue: C/D layout col = lane&15, row = (lane>>4)*4 + reg  [m89-verified]
  const int col0 = lane & 15;
  const int row0 = (lane >> 4) * 4;
#pragma unroll
  for (int ih = 0; ih < 2; ++ih)
#pragma unroll
    for (int jh = 0; jh < 2; ++jh)
#pragma unroll
      for (int j = 0; j < BJ; ++j) {
        const int gcol = bn + jh * (BN / 2) + wn * BC + j * 16 + col0;
        float bv = 0.f;
        if constexpr (ADD_BIAS) bv = bias[gcol];
#pragma unroll
        for (int i = 0; i < AI; ++i)
#pragma unroll
          for (int rr = 0; rr < 4; ++rr) {
            const int grow = bm + ih * 128 + wm * AR + i * 16 + row0 + rr;
            float v = acc[ih][jh][i][j][rr] + bv;
            if constexpr (OUT_BF16)
              ((u16*)Cv)[(size_t)grow * N + gcol] = f32_bf16(v);
            else
              ((float*)Cv)[(size_t)grow * N + gcol] = v;
          }
      }
#undef MFMA_Q
#undef LOAD_A
#undef LOAD_B
#undef STAGE_A
#undef STAGE_B
#undef BAR
#undef LGKM0
#undef PRIO1
#undef PRIO0
}

// ---------------- launch ----------------

extern "C" void kernel_launch(void* const* d_in, const int* in_sizes, int n_in,
                              void* d_out, int out_size, void* d_ws, size_t ws_size,
                              hipStream_t stream) {
  const float* x        = (const float*)d_in[0];
  const int*   U_data   = (const int*)d_in[1];
  const float* U_scale  = (const float*)d_in[2];
  const float* U_zp     = (const float*)d_in[3];
  const int*   S_data   = (const int*)d_in[4];
  const float* S_scale  = (const float*)d_in[5];
  const float* S_zp     = (const float*)d_in[6];
  const int*   Vh_data  = (const int*)d_in[7];
  const float* Vh_scale = (const float*)d_in[8];
  const float* Vh_zp    = (const float*)d_in[9];
  const float* bias     = (const float*)d_in[10];
  float* out = (float*)d_out;

  char* ws = (char*)d_ws;
  u16* xb  = (u16*)ws;                                  // 8192*4096*2  = 64 MiB
  u16* vhb = (u16*)(ws + (size_t)67108864);             // 1024*4096*2  =  8 MiB
  u16* ub  = (u16*)(ws + (size_t)67108864 + 8388608);   // 4096*1024*2  =  8 MiB
  u16* hb  = (u16*)(ws + (size_t)67108864 + 16777216);  // 8192*1024*2  = 16 MiB

  convert_x<<<NROWS * INF / (8 * 256), 256, 0, stream>>>(x, xb);
  dequant_vh<<<RNK * INF / (4 * 256), 256, 0, stream>>>(Vh_data, Vh_scale, Vh_zp,
                                                        S_data, S_scale, S_zp, vhb);
  dequant_u<<<OUTF * RNK / (4 * 256), 256, 0, stream>>>(U_data, U_scale, U_zp, ub);

  // GEMM1: h[8192,1024] = xb[8192,4096] @ vhb[1024,4096]^T   (bf16 out)
  // waves 4Mx2N (64x64/wave); m201 4-phase loop; XCD swizzle; vmcnt(5).
  gemm5<128, 4, 2, INF, RNK, true, false>
      <<<dim3(RNK / 128, NROWS / 256), 512, 0, stream>>>(xb, vhb, (void*)hb, nullptr);

  // GEMM2: y[8192,4096] = hb[8192,1024] @ ub[4096,1024]^T + bias   (fp32 out)
  // waves 2Mx4N (128x64/wave = m201 geometry); m201 4-phase loop; vmcnt(6).
  gemm5<256, 2, 4, RNK, OUTF, false, true>
      <<<dim3(OUTF / 256, NROWS / 256), 512, 0, stream>>>(hb, ub, (void*)out, bias);
}

// Round 6
// 412.982 us; speedup vs baseline: 1.0982x; 1.0982x over previous
//
#include <hip/hip_runtime.h>
#include <stdint.h>

#define NROWS 8192   // B*S_LEN = 4*2048
#define INF   4096
#define OUTF  4096
#define RNK   1024

typedef unsigned short u16;
typedef __attribute__((ext_vector_type(8))) short bf16x8;   // 8 bf16 = 4 VGPRs
typedef __attribute__((ext_vector_type(4))) float f32x4;
typedef __attribute__((ext_vector_type(8))) unsigned short u16x8;

__device__ __forceinline__ u16 f32_bf16(float f) {
  union { float f; uint32_t u; } v; v.f = f;
  return (u16)((v.u + 0x7FFF + ((v.u >> 16) & 1)) >> 16);
}

// ------------- fused conversion / dequant kernel (memory-bound) --------------
// One launch instead of three (saves 2 serial launch overheads; same bytes).
//   blocks [0, XB)        : convert x fp32 -> bf16          (8 elems/thread)
//   blocks [XB, XB+VB)    : dequant Vh (S folded into rows) (4 elems/thread)
//   blocks [XB+VB, total) : dequant U                       (4 elems/thread)

#define PP_XB (NROWS * INF / (8 * 256))   // 16384
#define PP_VB (RNK * INF / (4 * 256))     // 2048
#define PP_UB (OUTF * RNK / (4 * 256))    // 2048

__global__ __launch_bounds__(256) void preproc(const float* __restrict__ x,
                                               u16* __restrict__ xo,
                                               const int* __restrict__ vh,
                                               const float* __restrict__ vs,
                                               const float* __restrict__ vz,
                                               const int* __restrict__ sd,
                                               const float* __restrict__ ss,
                                               const float* __restrict__ sz,
                                               u16* __restrict__ vho,
                                               const int* __restrict__ ud,
                                               const float* __restrict__ us,
                                               const float* __restrict__ uz,
                                               u16* __restrict__ uo) {
  const int b = blockIdx.x;
  if (b < PP_XB) {
    int t = b * 256 + threadIdx.x;
    int e = t * 8;
    float4 a = *(const float4*)(x + e);
    float4 c = *(const float4*)(x + e + 4);
    u16x8 r;
    r[0] = f32_bf16(a.x); r[1] = f32_bf16(a.y); r[2] = f32_bf16(a.z); r[3] = f32_bf16(a.w);
    r[4] = f32_bf16(c.x); r[5] = f32_bf16(c.y); r[6] = f32_bf16(c.z); r[7] = f32_bf16(c.w);
    *(u16x8*)(xo + e) = r;
  } else if (b < PP_XB + PP_VB) {
    int t = (b - PP_XB) * 256 + threadIdx.x;
    int e = t * 4;
    int row = e >> 12;              // / INF
    float sval = ((float)sd[row] - sz[0]) * ss[0];
    float sc = vs[0] * sval;
    float zp = vz[0];
    int4 d = *(const int4*)(vh + e);
    ushort4 r;
    r.x = f32_bf16(((float)d.x - zp) * sc);
    r.y = f32_bf16(((float)d.y - zp) * sc);
    r.z = f32_bf16(((float)d.z - zp) * sc);
    r.w = f32_bf16(((float)d.w - zp) * sc);
    *(ushort4*)(vho + e) = r;
  } else {
    int t = (b - PP_XB - PP_VB) * 256 + threadIdx.x;
    int e = t * 4;
    float sc = us[0];
    float zp = uz[0];
    int4 d = *(const int4*)(ud + e);
    ushort4 r;
    r.x = f32_bf16(((float)d.x - zp) * sc);
    r.y = f32_bf16(((float)d.y - zp) * sc);
    r.z = f32_bf16(((float)d.z - zp) * sc);
    r.w = f32_bf16(((float)d.w - zp) * sc);
    *(ushort4*)(uo + e) = r;
  }
}

// ---------------- bf16 MFMA GEMM, C[m][n] = sum_k A[m][k]*B[n][k] ----------------
// Round-0 verified structure, UNCHANGED except the XCD-chunked block swizzle:
// 128x128 tile, BK=64, 4 waves (2x2), each wave 4x4 of 16x16x32 MFMA,
// global_load_lds width=16 staging, 32 KiB LDS -> ~3 blocks/CU co-resident
// (the inter-block overlap is what hides staging latency; every 512-thread
// 1-block/CU redesign in rounds 1-5 lost this and regressed).
//
// LDS layout is XOR-swizzled to kill the 16-way bank conflict of a plain
// row-major BK=64 tile: logical column-group cg (8 bf16 = 16 B) of row r is
// stored at physical slot (cg ^ (r & 7)). global_load_lds forces LDS dest =
// wave base + lane*16, so the swizzle is applied by permuting WHICH global
// 16B chunk each lane fetches (same cache-line set -> coalescing preserved).
//
// XCD swizzle (T1, proven r3: FETCH 266->74 MB): HW round-robins the linear
// workgroup id % 8 across XCDs; remap so XCD k owns a contiguous y-chunk of
// the grid -> both the A row-panels and the B panels become L2-local per XCD.

__device__ __forceinline__ void gl_lds16(const u16* g, u16* l) {
  __builtin_amdgcn_global_load_lds(
      (const __attribute__((address_space(1))) void*)g,
      (__attribute__((address_space(3))) void*)l, 16, 0, 0);
}

template <bool OUT_BF16, bool ADD_BIAS>
__global__ __launch_bounds__(256) void gemm_bt(const u16* __restrict__ A,
                                               const u16* __restrict__ B,
                                               void* __restrict__ Cv,
                                               const float* __restrict__ bias,
                                               const int N, const int K) {
  constexpr int BM = 128, BN = 128, BK = 64;
  __shared__ __attribute__((aligned(16))) u16 ldsA[BM * BK];
  __shared__ __attribute__((aligned(16))) u16 ldsB[BN * BK];

  const int tid  = threadIdx.x;
  const int lane = tid & 63;
  const int wave = tid >> 6;

  // T1: XCD-chunked bijective swizzle.  L = hw linear id (x fastest).
  const int nxb  = gridDim.x;
  const int cpx  = (gridDim.x * gridDim.y) >> 3;   // grid % 8 == 0 for both GEMMs
  const int L    = blockIdx.y * nxb + blockIdx.x;
  const int orig = (L & 7) * cpx + (L >> 3);
  const int bm = (orig / nxb) * BM;
  const int bn = (orig % nxb) * BN;

  const int wm = (wave >> 1) * 64;
  const int wn = (wave & 1) * 64;

  f32x4 acc[4][4] = {};

  // staging: thread t writes LDS physical slot (row = t>>3, cg' = t&7) at
  // byte offset t*16; it must therefore fetch global logical
  // cg = cg' ^ (row & 7).
  const int srow = tid >> 3;                       // 0..31
  const int scol = (((tid & 7) ^ (srow & 7)) * 8); // swizzled global column
  const int lcol = (tid & 7) * 8;                  // physical LDS column
  const u16* gA = A + (bm + srow) * K + scol;
  const u16* gB = B + (bn + srow) * K + scol;
  u16* lA = ldsA + srow * BK + lcol;
  u16* lB = ldsB + srow * BK + lcol;

  for (int kt = 0; kt < K; kt += BK) {
#pragma unroll
    for (int i = 0; i < 4; ++i) {
      // rows srow + 32*i: (row & 7) == (srow & 7), so swizzle term unchanged
      gl_lds16(gA + i * 32 * K + kt, lA + i * 32 * BK);
      gl_lds16(gB + i * 32 * K + kt, lB + i * 32 * BK);
    }
    __syncthreads();

    const int r  = lane & 15;
    const int kq = (lane >> 4) * 8;
#pragma unroll
    for (int ks = 0; ks < BK; ks += 32) {
      // logical column ks+kq -> physical ( ((ks+kq)/8) ^ (r&7) ) * 8
      const int pcol = (((ks + kq) >> 3) ^ (r & 7)) << 3;
      bf16x8 af[4], bfr[4];
#pragma unroll
      for (int i = 0; i < 4; ++i)
        af[i] = *(const bf16x8*)(ldsA + (wm + i * 16 + r) * BK + pcol);
#pragma unroll
      for (int j = 0; j < 4; ++j)
        bfr[j] = *(const bf16x8*)(ldsB + (wn + j * 16 + r) * BK + pcol);
#pragma unroll
      for (int i = 0; i < 4; ++i)
#pragma unroll
        for (int j = 0; j < 4; ++j)
          acc[i][j] = __builtin_amdgcn_mfma_f32_16x16x32_bf16(af[i], bfr[j], acc[i][j], 0, 0, 0);
    }
    __syncthreads();
  }

  // epilogue: C/D layout col = lane&15, row = (lane>>4)*4 + reg  [m89-verified]
  const int col0 = lane & 15;
  const int row0 = (lane >> 4) * 4;
#pragma unroll
  for (int i = 0; i < 4; ++i) {
#pragma unroll
    for (int j = 0; j < 4; ++j) {
      const int gcol = bn + wn + j * 16 + col0;
      float bv = 0.f;
      if (ADD_BIAS) bv = bias[gcol];
#pragma unroll
      for (int rr = 0; rr < 4; ++rr) {
        const int grow = bm + wm + i * 16 + row0 + rr;
        float v = acc[i][j][rr] + bv;
        if (OUT_BF16)
          ((u16*)Cv)[grow * N + gcol] = f32_bf16(v);
        else
          ((float*)Cv)[grow * N + gcol] = v;
      }
    }
  }
}

// ---------------- launch ----------------

extern "C" void kernel_launch(void* const* d_in, const int* in_sizes, int n_in,
                              void* d_out, int out_size, void* d_ws, size_t ws_size,
                              hipStream_t stream) {
  const float* x        = (const float*)d_in[0];
  const int*   U_data   = (const int*)d_in[1];
  const float* U_scale  = (const float*)d_in[2];
  const float* U_zp     = (const float*)d_in[3];
  const int*   S_data   = (const int*)d_in[4];
  const float* S_scale  = (const float*)d_in[5];
  const float* S_zp     = (const float*)d_in[6];
  const int*   Vh_data  = (const int*)d_in[7];
  const float* Vh_scale = (const float*)d_in[8];
  const float* Vh_zp    = (const float*)d_in[9];
  const float* bias     = (const float*)d_in[10];
  float* out = (float*)d_out;

  char* ws = (char*)d_ws;
  u16* xb  = (u16*)ws;                                  // 8192*4096*2  = 64 MiB
  u16* vhb = (u16*)(ws + (size_t)67108864);             // 1024*4096*2  =  8 MiB
  u16* ub  = (u16*)(ws + (size_t)67108864 + 8388608);   // 4096*1024*2  =  8 MiB
  u16* hb  = (u16*)(ws + (size_t)67108864 + 16777216);  // 8192*1024*2  = 16 MiB

  preproc<<<PP_XB + PP_VB + PP_UB, 256, 0, stream>>>(
      x, xb, Vh_data, Vh_scale, Vh_zp, S_data, S_scale, S_zp, vhb,
      U_data, U_scale, U_zp, ub);

  // GEMM1: h[8192,1024] = xb[8192,4096] @ vhb[1024,4096]^T   (bf16 out)
  gemm_bt<true, false><<<dim3(RNK / 128, NROWS / 128), 256, 0, stream>>>(
      xb, vhb, (void*)hb, nullptr, RNK, INF);
  // GEMM2: y[8192,4096] = hb[8192,1024] @ ub[4096,1024]^T + bias   (fp32 out)
  gemm_bt<false, true><<<dim3(OUTF / 128, NROWS / 128), 256, 0, stream>>>(
      hb, ub, (void*)out, bias, OUTF, RNK);
}